// Round 7
// baseline (141.002 us; speedup 1.0000x reference)
//
#include <hip/hip_runtime.h>

#define RADIUS 5
#define WIN 9
#define BB 4
#define KK 4
#define HH 224
#define WW 224
#define HW (HH * WW)
#define PD 234                 // HH + 2*RADIUS
#define PAREA (PD * PD)        // 54756
#define NBUCKET 64
#define PARTIAL_FLOATS (NBUCKET * BB * 8)   // 2048 floats = 8 KB
#define ZERO_FLOATS 2064                    // partials + counter + pad
#define BLOCKS_PER_B (HW / 64)              // 784
#define TOTAL_BLOCKS (BB * BLOCKS_PER_B)    // 3136
#define NW4 (BB * HW * 81 / 4)              // 4,064,256 float4 of weight
#define PAD_GRID 2048

// d_ws layout (floats):
//   [0, 2048)                      : partial buckets [bucket][b][8] (0..3 A_k, 4..7 V_k)
//   [2048]                         : block-completion counter (unsigned)
//   [2560, 2560 + B*PAREA*4)       : padded seg P[b][r][c][k], float4 per (r,c)

// ---------- pre-pass: zero partials/counter, build padded seg, prefetch weight into L3 ----------
__global__ __launch_bounds__(256) void ncuts_pad(
    const float* __restrict__ seg, float4* __restrict__ pseg, float* __restrict__ zr,
    const float4* __restrict__ w4)
{
    const int tid = blockIdx.x * 256 + threadIdx.x;
    if (tid < ZERO_FLOATS) zr[tid] = 0.f;           // partial buckets + counter

    if (tid < BB * PAREA) {
        const int b  = tid / PAREA;
        const int rc = tid - b * PAREA;
        const int r  = rc / PD;
        const int c  = rc - r * PD;
        const int hh = r - RADIUS;
        const int ww = c - RADIUS;
        float4 v = {0.f, 0.f, 0.f, 0.f};
        if (hh >= 0 && hh < HH && ww >= 0 && ww < WW) {
            const float* sb = seg + (size_t)b * KK * HW + hh * WW + ww;
            v.x = sb[0 * HW];
            v.y = sb[1 * HW];
            v.z = sb[2 * HW];
            v.w = sb[3 * HW];
        }
        pseg[tid] = v;
    }

    // streaming prefetch of the full weight tensor (65 MB) into L3.
    // Also serves as an in-situ read-BW probe right after the harness's 268 MB fill:
    // if this kernel shows up at ~25-35 us in the profile, post-fill read BW is the wall.
    float acc = 0.f;
    for (int i = tid; i < NW4; i += PAD_GRID * 256) {
        const float4 v = w4[i];
        acc += v.x + v.y + v.z + v.w;
    }
    asm volatile("" :: "v"(acc));   // keep the loads alive (no DCE)
}

// ---------- main: one wave = 64 consecutive pixels; last block folds + writes loss ----------
__global__ __launch_bounds__(64) void ncuts_main(
    const float* __restrict__ weight,
    const float4* __restrict__ pseg,
    float* __restrict__ partial,
    unsigned* __restrict__ counter,
    float* __restrict__ out)
{
    __shared__ float wlds[64 * 81];   // 20736 B -> 7 blocks/CU

    const int lane = threadIdx.x;     // 0..63
    const int tid  = blockIdx.x * 64 + lane;   // pixel id
    const int b    = tid / HW;        // uniform per block (784 blocks per b)
    const int rem  = tid - b * HW;
    const int h    = rem / WW;
    const int w    = rem - h * WW;

    // --- stage this wave's 64*81 weights into LDS via LDS-DMA (lane-linear layout) ---
    const float4* wsrc = (const float4*)(weight + (size_t)blockIdx.x * (64 * 81));
    float4* ldsb = (float4*)wlds;
    #pragma unroll
    for (int j = 0; j < 20; ++j)
        __builtin_amdgcn_global_load_lds(
            (__attribute__((address_space(1))) void*)(wsrc + j * 64 + lane),
            (__attribute__((address_space(3))) void*)(ldsb + j * 64),
            16, 0, 0);
    if (lane < 16)
        __builtin_amdgcn_global_load_lds(
            (__attribute__((address_space(1))) void*)(wsrc + 1280 + lane),
            (__attribute__((address_space(3))) void*)(ldsb + 1280),
            16, 0, 0);

    const float4* p4 = pseg + (size_t)b * PAREA;
    // center load issues before the drain -> latency hidden under the DMA
    const float4 t = p4[(h + RADIUS) * PD + (w + RADIUS)];

    __syncthreads();   // vmcnt(0) drain of the LDS-DMA

    const float* wl = &wlds[lane * 81];

    float a0 = 0.f, a1 = 0.f, a2 = 0.f, a3 = 0.f, wsum = 0.f;

    #pragma unroll
    for (int m = 0; m < WIN; ++m) {
        const int base = (h + m) * PD + w;
        #pragma unroll
        for (int n = 0; n < WIN; ++n) {
            const float wv = wl[m * WIN + n];
            const float4 s = p4[base + n];
            a0 = fmaf(wv, s.x, a0);
            a1 = fmaf(wv, s.y, a1);
            a2 = fmaf(wv, s.z, a2);
            a3 = fmaf(wv, s.w, a3);
            wsum += wv;
        }
    }

    float vals[8] = { a0 * t.x, a1 * t.y, a2 * t.z, a3 * t.w,
                      wsum * t.x, wsum * t.y, wsum * t.z, wsum * t.w };

    #pragma unroll
    for (int i = 0; i < 8; ++i) {
        float v = vals[i];
        v += __shfl_down(v, 32);
        v += __shfl_down(v, 16);
        v += __shfl_down(v, 8);
        v += __shfl_down(v, 4);
        v += __shfl_down(v, 2);
        v += __shfl_down(v, 1);
        vals[i] = v;
    }

    if (lane == 0) {
        const int bb     = blockIdx.x - b * BLOCKS_PER_B;
        const int bucket = bb & (NBUCKET - 1);
        float* dst = partial + (bucket * BB + b) * 8;
        #pragma unroll
        for (int i = 0; i < 8; ++i)
            atomicAdd(dst + i, vals[i]);
    }

    // --- fence-free fused finalization ---
    // Release: wait until this block's bucket atomics reached the coherence point.
    // (No cache writeback/invalidate needed: atomics bypass the non-coherent L2s.)
    asm volatile("s_waitcnt vmcnt(0)" ::: "memory");
    unsigned old = 0;
    if (lane == 0) old = atomicAdd(counter, 1u);
    old = (unsigned)__shfl((int)old, 0);

    if (old == TOTAL_BLOCKS - 1) {
        // Winner: all other blocks' atomics are at the coherence point.
        // Read partials with agent-scope atomic loads (bypass stale L1/L2).
        float s = 0.f;
        if (lane < 32) {                         // lane = b*8 + i
            #pragma unroll 8
            for (int bucket = 0; bucket < NBUCKET; ++bucket)
                s += __hip_atomic_load(partial + bucket * 32 + lane,
                                       __ATOMIC_RELAXED, __HIP_MEMORY_SCOPE_AGENT);
        }
        const float sv   = __shfl(s, lane + 4);              // matching V for A-lanes
        float term = (lane < 32 && (lane & 7) < 4) ? (s / sv) : 0.f;
        term += __shfl_down(term, 32);
        term += __shfl_down(term, 16);
        term += __shfl_down(term, 8);
        term += __shfl_down(term, 4);
        term += __shfl_down(term, 2);
        term += __shfl_down(term, 1);
        if (lane == 0)
            out[0] = (float)(BB * KK) - term;    // sum_b (K - sum_k A/V)
    }
}

extern "C" void kernel_launch(void* const* d_in, const int* in_sizes, int n_in,
                              void* d_out, int out_size, void* d_ws, size_t ws_size,
                              hipStream_t stream) {
    const float* seg    = (const float*)d_in[0];
    const float* weight = (const float*)d_in[1];
    float* out        = (float*)d_out;
    float* wsf        = (float*)d_ws;
    float* partial    = wsf;                          // 2048 floats
    unsigned* counter = (unsigned*)(wsf + 2048);
    float4* pseg      = (float4*)(wsf + 2560);        // byte offset 10240, 16B aligned

    // pre-pass: zero partials/counter + padded seg + weight L3-prefetch (read-BW probe)
    hipLaunchKernelGGL(ncuts_pad, dim3(PAD_GRID), dim3(256), 0, stream,
                       seg, pseg, wsf, (const float4*)weight);

    // main + fence-free fused finalization (last block writes the loss)
    hipLaunchKernelGGL(ncuts_main, dim3(TOTAL_BLOCKS), dim3(64), 0, stream,
                       weight, pseg, partial, counter, out);
}

// Round 8
// 104.149 us; speedup vs baseline: 1.3538x; 1.3538x over previous
//
#include <hip/hip_runtime.h>

#define RADIUS 5
#define WIN 9
#define BB 4
#define KK 4
#define HH 224
#define WW 224
#define HW (HH * WW)
#define PD 234                 // HH + 2*RADIUS
#define PAREA (PD * PD)        // 54756
#define NBUCKET 64
#define PARTIAL_FLOATS (NBUCKET * BB * 8)   // 2048 floats = 8 KB
#define BLOCKS_PER_B (HW / 64)              // 784
#define TOTAL_BLOCKS (BB * BLOCKS_PER_B)    // 3136

// d_ws layout (floats):
//   [0, 2048)                      : partial buckets [bucket][b][8] (0..3 A_k, 4..7 V_k)
//   [2048, 2048 + B*PAREA*4)       : padded seg P[b][r][c][k], float4 per (r,c)

// ---------- pre-pass: zero partials + seg [B,K,H,W] -> zero-padded [B,PD,PD,K] ----------
__global__ __launch_bounds__(256) void ncuts_pad(
    const float* __restrict__ seg, float4* __restrict__ pseg, float* __restrict__ zr)
{
    const int tid = blockIdx.x * 256 + threadIdx.x;
    if (tid < PARTIAL_FLOATS) zr[tid] = 0.f;        // partial buckets
    if (tid >= BB * PAREA) return;
    const int b  = tid / PAREA;
    const int rc = tid - b * PAREA;
    const int r  = rc / PD;
    const int c  = rc - r * PD;
    const int hh = r - RADIUS;
    const int ww = c - RADIUS;
    float4 v = {0.f, 0.f, 0.f, 0.f};
    if (hh >= 0 && hh < HH && ww >= 0 && ww < WW) {
        const float* sb = seg + (size_t)b * KK * HW + hh * WW + ww;
        v.x = sb[0 * HW];
        v.y = sb[1 * HW];
        v.z = sb[2 * HW];
        v.w = sb[3 * HW];
    }
    pseg[tid] = v;
}

// ---------- main: one wave = 64 consecutive pixels, row-batched loads for MLP ----------
// __launch_bounds__(64,1): LDS already caps residency at 7 blocks/CU (1.75 waves/SIMD),
// so free the register allocator to keep a full window row (+next) in flight.
__global__ __launch_bounds__(64, 1) void ncuts_main(
    const float* __restrict__ weight,
    const float4* __restrict__ pseg,
    float* __restrict__ partial)
{
    __shared__ float wlds[64 * 81];   // 20736 B -> 7 blocks/CU

    const int lane = threadIdx.x;     // 0..63
    const int tid  = blockIdx.x * 64 + lane;   // pixel id
    const int b    = tid / HW;        // uniform per block (784 blocks per b)
    const int rem  = tid - b * HW;
    const int h    = rem / WW;
    const int w    = rem - h * WW;

    // --- stage this wave's 64*81 weights into LDS via LDS-DMA (lane-linear layout) ---
    const float4* wsrc = (const float4*)(weight + (size_t)blockIdx.x * (64 * 81));
    float4* ldsb = (float4*)wlds;
    #pragma unroll
    for (int j = 0; j < 20; ++j)
        __builtin_amdgcn_global_load_lds(
            (__attribute__((address_space(1))) void*)(wsrc + j * 64 + lane),
            (__attribute__((address_space(3))) void*)(ldsb + j * 64),
            16, 0, 0);
    if (lane < 16)
        __builtin_amdgcn_global_load_lds(
            (__attribute__((address_space(1))) void*)(wsrc + 1280 + lane),
            (__attribute__((address_space(3))) void*)(ldsb + 1280),
            16, 0, 0);

    const float4* p4 = pseg + (size_t)b * PAREA;
    // center load issues before the drain -> latency hidden under the DMA
    const float4 t = p4[(h + RADIUS) * PD + (w + RADIUS)];

    __syncthreads();   // vmcnt(0) drain of the LDS-DMA

    const float* wl = &wlds[lane * 81];

    float a0 = 0.f, a1 = 0.f, a2 = 0.f, a3 = 0.f, wsum = 0.f;

    #pragma unroll
    for (int m = 0; m < WIN; ++m) {
        const int base = (h + m) * PD + w;

        // batch the whole row's loads first (static indexing -> stays in VGPRs),
        // so 9+ loads are in flight before the first dependent FMA
        float4 row[WIN];
        #pragma unroll
        for (int n = 0; n < WIN; ++n)
            row[n] = p4[base + n];

        #pragma unroll
        for (int n = 0; n < WIN; ++n) {
            const float wv = wl[m * WIN + n];
            a0 = fmaf(wv, row[n].x, a0);
            a1 = fmaf(wv, row[n].y, a1);
            a2 = fmaf(wv, row[n].z, a2);
            a3 = fmaf(wv, row[n].w, a3);
            wsum += wv;
        }
    }

    float vals[8] = { a0 * t.x, a1 * t.y, a2 * t.z, a3 * t.w,
                      wsum * t.x, wsum * t.y, wsum * t.z, wsum * t.w };

    #pragma unroll
    for (int i = 0; i < 8; ++i) {
        float v = vals[i];
        v += __shfl_down(v, 32);
        v += __shfl_down(v, 16);
        v += __shfl_down(v, 8);
        v += __shfl_down(v, 4);
        v += __shfl_down(v, 2);
        v += __shfl_down(v, 1);
        vals[i] = v;
    }

    if (lane == 0) {
        const int bb     = blockIdx.x - b * BLOCKS_PER_B;
        const int bucket = bb & (NBUCKET - 1);
        float* dst = partial + (bucket * BB + b) * 8;
        #pragma unroll
        for (int i = 0; i < 8; ++i)
            atomicAdd(dst + i, vals[i]);
    }
}

// ---------- final: fold buckets, compute loss ----------
__global__ __launch_bounds__(64) void ncuts_final(
    const float* __restrict__ partial, float* __restrict__ out)
{
    __shared__ float sums[32];
    const int t = threadIdx.x;
    if (t < 32) {
        float s = 0.f;
        for (int bucket = 0; bucket < NBUCKET; ++bucket)
            s += partial[bucket * 32 + t];
        sums[t] = s;
    }
    __syncthreads();
    if (t == 0) {
        float total = 0.f;
        for (int b = 0; b < BB; ++b) {
            float assoc = 0.f;
            for (int k = 0; k < KK; ++k) {
                const float A = sums[b * 8 + k];
                const float V = sums[b * 8 + 4 + k];
                assoc += A / V;
            }
            total += (float)KK - assoc;
        }
        out[0] = total;
    }
}

extern "C" void kernel_launch(void* const* d_in, const int* in_sizes, int n_in,
                              void* d_out, int out_size, void* d_ws, size_t ws_size,
                              hipStream_t stream) {
    const float* seg    = (const float*)d_in[0];
    const float* weight = (const float*)d_in[1];
    float* out     = (float*)d_out;
    float* wsf     = (float*)d_ws;
    float* partial = wsf;                               // 2048 floats
    float4* pseg   = (float4*)(wsf + PARTIAL_FLOATS);   // byte offset 8192, 16B aligned

    // pre-pass: zero partials + build padded seg (no separate memset dispatch)
    {
        const int total = BB * PAREA;           // 219024
        const int grid  = (total + 255) / 256;  // 856
        hipLaunchKernelGGL(ncuts_pad, dim3(grid), dim3(256), 0, stream, seg, pseg, wsf);
    }

    // main
    hipLaunchKernelGGL(ncuts_main, dim3(TOTAL_BLOCKS), dim3(64), 0, stream,
                       weight, pseg, partial);

    // final: fold buckets, write loss
    hipLaunchKernelGGL(ncuts_final, dim3(1), dim3(64), 0, stream, partial, out);
}